// Round 4
// baseline (263.749 us; speedup 1.0000x reference)
//
#include <hip/hip_runtime.h>
#include <math.h>

// Round 11: barrier-free LDS-free flash.
//   K/V per (b,h) = 256KB, G per XCD = 2.1MB -> all L2-resident (FETCH=20MB
//   proved it).  LDS staging gave zero sharing (every wave reads the whole
//   tile) and cost 2 barriers + DMA sync + bank conflicts per iter.  Now:
//   - K/V/G fragments loaded straight from global (L1/L2), K double-buffered
//     in regs, V+G single-buffered (issued at iter top, used 300-500cy later)
//   - P built in-register: v_cvt_pk_bf16_f32 + v_permlane32_swap_b32 (T12)
//     exchanges kv-halves between lane and lane^32 -> PV B-frags, no LDS
//   - zero barriers, zero LDS, waves fully independent, compiler-auto waits
//   prep / gemm / vtrans unchanged from R10.

#define BS 8
#define SEQ 1024
#define DM 512
#define NH 8
#define DK 64
#define ROWS (BS * SEQ)

typedef __bf16 bf16_t;
typedef bf16_t bf16x8 __attribute__((ext_vector_type(8)));
typedef bf16_t bf16x4 __attribute__((ext_vector_type(4)));
typedef float f32x4 __attribute__((ext_vector_type(4)));
typedef float f32x16 __attribute__((ext_vector_type(16)));
typedef unsigned int uint32_t_;
typedef unsigned int uintx4 __attribute__((ext_vector_type(4)));

__device__ inline f32x4 mfma32(bf16x8 a, bf16x8 b, f32x4 c) {
  return __builtin_amdgcn_mfma_f32_16x16x32_bf16(a, b, c, 0, 0, 0);
}
__device__ inline f32x16 mfma3232(bf16x8 a, bf16x8 b, f32x16 c) {
  return __builtin_amdgcn_mfma_f32_32x32x16_bf16(a, b, c, 0, 0, 0);
}

// async global->LDS, 16 bytes/lane (gemm only).
__device__ inline void gload_lds16(const bf16_t* g, bf16_t* l) {
  __builtin_amdgcn_global_load_lds(
      (const __attribute__((address_space(1))) void*)g,
      (__attribute__((address_space(3))) void*)l, 16, 0, 0);
}

__device__ inline unsigned cvtpk_bf16(float lo, float hi) {
  unsigned d;
  asm("v_cvt_pk_bf16_f32 %0, %1, %2" : "=v"(d) : "v"(lo), "v"(hi));
  return d;
}
// x.hi-lanes <-> y.lo-lanes.  After: x = {x.lo, y.lo}, y = {x.hi, y.hi}.
__device__ inline void plswap(unsigned& x, unsigned& y) {
  asm("v_permlane32_swap_b32 %0, %1" : "+v"(x), "+v"(y));
}

// ---------------------------------------------------------------------------
// prep: fused {fp32->bf16 conversion} + {G2 = (1+softmax(wc))*0.125*log2e}.
// ---------------------------------------------------------------------------
__global__ __launch_bounds__(256) void prep_kernel(
    const float* q, const float* k, const float* v,
    const float* wq, const float* wk, const float* wv, const float* wo,
    bf16_t* xq, bf16_t* xk, bf16_t* xv,
    bf16_t* wqb, bf16_t* wkb, bf16_t* wvb, bf16_t* wob,
    const float* __restrict__ wc, bf16_t* __restrict__ G) {
  int bx = blockIdx.x;
  int t = threadIdx.x;
  if (bx < 1664) {
    const float* srcs[7] = {q, k, v, wq, wk, wv, wo};
    bf16_t* dsts[7] = {xq, xk, xv, wqb, wkb, wvb, wob};
    int seg, boff;
    if (bx < 1536) { seg = bx >> 9; boff = bx & 511; }
    else { seg = 3 + ((bx - 1536) >> 5); boff = (bx - 1536) & 31; }
    const float* src = srcs[seg] + (size_t)boff * 8192;
    bf16_t* dst = dsts[seg] + (size_t)boff * 8192;
#pragma unroll
    for (int f = 0; f < 8; ++f) {
      int idx = (f * 256 + t) * 4;
      float4 x = *(const float4*)(src + idx);
      bf16x4 o;
      o[0] = (bf16_t)x.x; o[1] = (bf16_t)x.y; o[2] = (bf16_t)x.z; o[3] = (bf16_t)x.w;
      *(bf16x4*)(dst + idx) = o;
    }
  } else {
    int row = bx - 1664;
    const float* x = wc + (size_t)row * SEQ;
    bf16_t* y = G + (size_t)row * SEQ;
    float4 vv = *(const float4*)(x + t * 4);
    float m = fmaxf(fmaxf(vv.x, vv.y), fmaxf(vv.z, vv.w));
#pragma unroll
    for (int off = 32; off > 0; off >>= 1) m = fmaxf(m, __shfl_xor(m, off, 64));
    __shared__ float sm[4], ss[4];
    int w = t >> 6;
    if ((t & 63) == 0) sm[w] = m;
    __syncthreads();
    m = fmaxf(fmaxf(sm[0], sm[1]), fmaxf(sm[2], sm[3]));
    float4 e;
    e.x = __expf(vv.x - m); e.y = __expf(vv.y - m);
    e.z = __expf(vv.z - m); e.w = __expf(vv.w - m);
    float s = e.x + e.y + e.z + e.w;
#pragma unroll
    for (int off = 32; off > 0; off >>= 1) s += __shfl_xor(s, off, 64);
    if ((t & 63) == 0) ss[w] = s;
    __syncthreads();
    s = ss[0] + ss[1] + ss[2] + ss[3];
    float inv = 1.0f / s;
    const float SC = 0.18033688011112042f;  // 0.125 * log2(e)
    bf16x4 g;
    g[0] = (bf16_t)((1.0f + e.x * inv) * SC);
    g[1] = (bf16_t)((1.0f + e.y * inv) * SC);
    g[2] = (bf16_t)((1.0f + e.z * inv) * SC);
    g[3] = (bf16_t)((1.0f + e.w * inv) * SC);
    *(bf16x4*)(y + t * 4) = g;
  }
}

// ---------------------------------------------------------------------------
// Core bf16 GEMM: C[M,512] = X @ W^T + bias.  BN=128, BK=32, BM in {64,128}.
// ---------------------------------------------------------------------------
template <int BM, bool OUTF32>
__device__ inline void gemm_core(const bf16_t* X, const bf16_t* W,
                                 const float* bias, void* Cv,
                                 int mblk, int nblk) {
  __shared__ bf16_t As[2][BM * 32];
  __shared__ bf16_t Bs[2][128 * 32];
  int t = threadIdx.x, lane = t & 63, w = t >> 6;
  int quad = lane >> 4, l15 = lane & 15;
  constexpr int MT = BM / 32;
  int m0w = (w & 1) * (BM / 2), n0w = (w >> 1) * 64;
  int mbase = mblk * BM, nbase = nblk * 128;
  int lr = lane >> 2, l4 = lane & 3;
  f32x4 acc[MT][4] = {};

#pragma unroll
  for (int f = 0; f < BM / 64; ++f) {
    int i = f * 4 + w;
    gload_lds16(X + (size_t)(mbase + i * 16 + lr) * DM + l4 * 8, &As[0][i * 512]);
  }
#pragma unroll
  for (int f = 0; f < 2; ++f) {
    int i = f * 4 + w;
    gload_lds16(W + (size_t)(nbase + i * 16 + lr) * DM + l4 * 8, &Bs[0][i * 512]);
  }

  for (int it = 0; it < 16; ++it) {
    __syncthreads();
    int cb = it & 1;
    if (it + 1 < 16) {
      int kb = (it + 1) * 32, nb = (it + 1) & 1;
#pragma unroll
      for (int f = 0; f < BM / 64; ++f) {
        int i = f * 4 + w;
        gload_lds16(X + (size_t)(mbase + i * 16 + lr) * DM + kb + l4 * 8, &As[nb][i * 512]);
      }
#pragma unroll
      for (int f = 0; f < 2; ++f) {
        int i = f * 4 + w;
        gload_lds16(W + (size_t)(nbase + i * 16 + lr) * DM + kb + l4 * 8, &Bs[nb][i * 512]);
      }
    }
    bf16x8 af[MT], bfr[4];
#pragma unroll
    for (int mt = 0; mt < MT; ++mt)
      af[mt] = *(const bf16x8*)&As[cb][(m0w + mt * 16 + l15) * 32 + quad * 8];
#pragma unroll
    for (int nt = 0; nt < 4; ++nt)
      bfr[nt] = *(const bf16x8*)&Bs[cb][(n0w + nt * 16 + l15) * 32 + quad * 8];
#pragma unroll
    for (int mt = 0; mt < MT; ++mt)
#pragma unroll
      for (int nt = 0; nt < 4; ++nt)
        acc[mt][nt] = mfma32(af[mt], bfr[nt], acc[mt][nt]);
  }

#pragma unroll
  for (int nt = 0; nt < 4; ++nt) {
    int col = nbase + n0w + nt * 16 + l15;
    float bc = bias[col];
#pragma unroll
    for (int mt = 0; mt < MT; ++mt)
#pragma unroll
      for (int r = 0; r < 4; ++r) {
        int row = mbase + m0w + mt * 16 + quad * 4 + r;
        float vv = acc[mt][nt][r] + bc;
        if (OUTF32)
          ((float*)Cv)[(size_t)row * DM + col] = vv;
        else
          ((bf16_t*)Cv)[(size_t)row * DM + col] = (bf16_t)vv;
      }
  }
}

__global__ __launch_bounds__(256) void gemm_qkv_kernel(
    const bf16_t* xq, const bf16_t* xk, const bf16_t* xv,
    const bf16_t* wq, const bf16_t* wk, const bf16_t* wv,
    const float* bq, const float* bk, const float* bv,
    bf16_t* cq, bf16_t* ck, bf16_t* cv) {
  const bf16_t* Xarr[3] = {xq, xk, xv};
  const bf16_t* Warr[3] = {wq, wk, wv};
  const float* barr[3] = {bq, bk, bv};
  bf16_t* Carr[3] = {cq, ck, cv};
  int z = blockIdx.z;
  gemm_core<128, false>(Xarr[z], Warr[z], barr[z], Carr[z], blockIdx.x, blockIdx.y);
}

__global__ __launch_bounds__(256) void gemm_wo_kernel(const bf16_t* X, const bf16_t* W,
                                                      const float* bias, float* C) {
  gemm_core<64, true>(X, W, bias, C, blockIdx.x, blockIdx.y);
}

// ---------------------------------------------------------------------------
// Vt[(b*8+h)*64 + d][m] = Vb[b*1024 + m][h*64 + d]
// ---------------------------------------------------------------------------
__global__ __launch_bounds__(256) void vtrans_kernel(const bf16_t* __restrict__ Vb,
                                                     bf16_t* __restrict__ Vt) {
  int mt = blockIdx.x;
  int bh = blockIdx.y;
  int b = bh >> 3, h = bh & 7;
  __shared__ bf16_t Ts[64][66];
  int t = threadIdx.x;
#pragma unroll
  for (int f = 0; f < 2; ++f) {
    int chunk = t + f * 256;
    int row = chunk >> 3;
    int c8 = (chunk & 7) * 8;
    bf16x8 v = *(const bf16x8*)&Vb[(size_t)(b * SEQ + mt * 64 + row) * DM + h * DK + c8];
#pragma unroll
    for (int j = 0; j < 8; ++j) Ts[c8 + j][row] = v[j];
  }
  __syncthreads();
#pragma unroll
  for (int f = 0; f < 2; ++f) {
    int chunk = t + f * 256;
    int d = chunk >> 3;
    int m8 = (chunk & 7) * 8;
    bf16x8 o;
#pragma unroll
    for (int j = 0; j < 8; ++j) o[j] = Ts[d][m8 + j];
    *(bf16x8*)&Vt[((size_t)(bh * DK + d)) * SEQ + mt * 64 + m8] = o;
  }
}

// ---------------------------------------------------------------------------
// Flash attention, R11: no LDS, no barriers.  Block = 4 independent waves,
// each owns 32 q rows of (b,h,qt).  32x32x16 MFMA, swapped QK^T.
//   st reg r (of 16) <-> kv = (r&3) + 8*(r>>2) + 4*lh, q = l31.
//   PV B-frag for step ks needs P[kv = ks*16 + lh*8 + j][q].  Lane owns half
//   those kv; lane^32 owns the other half -> cvt_pk pairs + permlane32_swap:
//     swap(cvtpk(p0,p1), cvtpk(p4,p5)) -> dwords 0,2; (p2,p3),(p6,p7) -> 1,3.
//   K double-buffered in regs (issued after last use, consumed next iter);
//   V,G single-buffered (issued at iter top, used 300-500cy later; L2-hit).
// ---------------------------------------------------------------------------
__global__ __launch_bounds__(256, 2) void flash_mfma_kernel(
    const bf16_t* __restrict__ Qb, const bf16_t* __restrict__ Kb,
    const bf16_t* __restrict__ Vt, const bf16_t* __restrict__ G,
    bf16_t* __restrict__ Ab) {
  // XCD swizzle: XCD x owns batch b=x.  grid (8,8,8) -> flat in [0,512).
  int flat = blockIdx.x + 8 * (blockIdx.y + 8 * blockIdx.z);
  int l = (flat & 7) * 64 + (flat >> 3);
  int qt = l & 7, h = (l >> 3) & 7, b = l >> 6;

  int t = threadIdx.x, lane = t & 63, w = t >> 6;
  int l31 = lane & 31, lh = lane >> 5;

  const bf16_t* Kbase = Kb + (size_t)(b * SEQ) * DM + h * DK;
  const bf16_t* Vbase = Vt + (size_t)((b * NH + h) * DK) * SEQ;

  // Q fragments (B-operand: col=q=l31, k=d slice lh*8).
  size_t qrow_g = (size_t)(b * SEQ + qt * 128 + w * 32 + l31) * DM + h * DK;
  bf16x8 aq[4];
#pragma unroll
  for (int ks = 0; ks < 4; ++ks)
    aq[ks] = *(const bf16x8*)&Qb[qrow_g + ks * 16 + lh * 8];

  const size_t grow = (size_t)(b * SEQ + qt * 128 + w * 32 + l31) * SEQ;

  float l_st = 0.f;
  f32x16 o0 = {}, o1 = {};

  bf16x8 kA[8], kB[8];
  // prologue: K(0) into kA
#pragma unroll
  for (int ks = 0; ks < 4; ++ks) {
    kA[ks * 2] = *(const bf16x8*)&Kbase[(size_t)(l31)*DM + ks * 16 + lh * 8];
    kA[ks * 2 + 1] = *(const bf16x8*)&Kbase[(size_t)(32 + l31) * DM + ks * 16 + lh * 8];
  }

  auto body = [&](int mt, bf16x8(&kU)[8], bf16x8(&kP)[8]) {
    // V(mt), G(mt): issue now, used after QK (~300-500 cy) -> L2 latency hidden
    bf16x8 vf[8];
#pragma unroll
    for (int ks = 0; ks < 4; ++ks) {
      vf[ks * 2] = *(const bf16x8*)&Vbase[(size_t)(l31)*SEQ + mt * 64 + ks * 16 + lh * 8];
      vf[ks * 2 + 1] =
          *(const bf16x8*)&Vbase[(size_t)(32 + l31) * SEQ + mt * 64 + ks * 16 + lh * 8];
    }
    bf16x4 gr[8];
#pragma unroll
    for (int kt = 0; kt < 2; ++kt)
#pragma unroll
      for (int g4 = 0; g4 < 4; ++g4)
        gr[kt * 4 + g4] =
            *(const bf16x4*)&G[grow + mt * 64 + kt * 32 + g4 * 8 + lh * 4];

    // QK^T: st0 = S^T[kv 0-31][q], st1 = S^T[kv 32-63][q]
    f32x16 st0 = {}, st1 = {};
    __builtin_amdgcn_s_setprio(1);
#pragma unroll
    for (int ks = 0; ks < 4; ++ks) {
      st0 = mfma3232(kU[ks * 2], aq[ks], st0);
      st1 = mfma3232(kU[ks * 2 + 1], aq[ks], st1);
    }
    __builtin_amdgcn_s_setprio(0);

    // prefetch K(mt+1) into kP (kU fully consumed)
    if (mt < 15) {
      const bf16_t* Kn = Kbase + (size_t)(mt + 1) * 64 * DM;
#pragma unroll
      for (int ks = 0; ks < 4; ++ks) {
        kP[ks * 2] = *(const bf16x8*)&Kn[(size_t)(l31)*DM + ks * 16 + lh * 8];
        kP[ks * 2 + 1] = *(const bf16x8*)&Kn[(size_t)(32 + l31) * DM + ks * 16 + lh * 8];
      }
    }

    // softmax: p = exp2(s * g2), accumulate row-sum (lane^32 merged at end)
    float pe0[16], pe1[16];
    float rs = 0.f;
#pragma unroll
    for (int g4 = 0; g4 < 4; ++g4)
#pragma unroll
      for (int rr = 0; rr < 4; ++rr) {
        int r = g4 * 4 + rr;
        float p0 = __builtin_amdgcn_exp2f(st0[r] * (float)gr[g4][rr]);
        float p1 = __builtin_amdgcn_exp2f(st1[r] * (float)gr[4 + g4][rr]);
        pe0[r] = p0; pe1[r] = p1;
        rs += p0 + p1;
      }
    l_st += rs;

    // PV: build B-frags in-register (cvt_pk + permlane32_swap), accumulate o
    __builtin_amdgcn_s_setprio(1);
#pragma unroll
    for (int ks = 0; ks < 4; ++ks) {
      const float* pe = (ks < 2) ? pe0 : pe1;
      int base = (ks & 1) * 8;
      unsigned d0 = cvtpk_bf16(pe[base + 0], pe[base + 1]);
      unsigned d1 = cvtpk_bf16(pe[base + 2], pe[base + 3]);
      unsigned d2 = cvtpk_bf16(pe[base + 4], pe[base + 5]);
      unsigned d3 = cvtpk_bf16(pe[base + 6], pe[base + 7]);
      plswap(d0, d2);  // d0 -> dword0, d2 -> dword2
      plswap(d1, d3);  // d1 -> dword1, d3 -> dword3
      uintx4 du = {d0, d1, d2, d3};
      bf16x8 bp = __builtin_bit_cast(bf16x8, du);
      o0 = mfma3232(vf[ks * 2], bp, o0);
      o1 = mfma3232(vf[ks * 2 + 1], bp, o1);
    }
    __builtin_amdgcn_s_setprio(0);
  };

#pragma unroll 1
  for (int mt = 0; mt < 16; mt += 2) {
    body(mt, kA, kB);
    body(mt + 1, kB, kA);
  }

  // lane^32 holds complementary kv set for the same q
  l_st += __shfl_xor(l_st, 32, 64);
  float linv = 1.0f / l_st;

  // o reg r: d = dt*32 + (r&3) + 8*(r>>2) + 4*lh, q = l31
#pragma unroll
  for (int dt = 0; dt < 2; ++dt) {
    const f32x16& o = dt ? o1 : o0;
#pragma unroll
    for (int g4 = 0; g4 < 4; ++g4) {
      bf16x4 ov;
#pragma unroll
      for (int rr = 0; rr < 4; ++rr) ov[rr] = (bf16_t)(o[g4 * 4 + rr] * linv);
      *(bf16x4*)&Ab[qrow_g + dt * 32 + g4 * 8 + lh * 4] = ov;
    }
  }
}

// ---------------------------------------------------------------------------
extern "C" void kernel_launch(void* const* d_in, const int* in_sizes, int n_in,
                              void* d_out, int out_size, void* d_ws, size_t ws_size,
                              hipStream_t stream) {
  const float* query = (const float*)d_in[0];
  const float* key = (const float*)d_in[1];
  const float* value = (const float*)d_in[2];
  const float* wc = (const float*)d_in[3];
  const float* Wq = (const float*)d_in[4];
  const float* bq = (const float*)d_in[5];
  const float* Wk = (const float*)d_in[6];
  const float* bk = (const float*)d_in[7];
  const float* Wv = (const float*)d_in[8];
  const float* bv = (const float*)d_in[9];
  const float* Wo = (const float*)d_in[10];
  const float* bo = (const float*)d_in[11];
  float* out = (float*)d_out;

  const size_t ACT = (size_t)ROWS * DM;
  const size_t WSZ = (size_t)DM * DM;
  bf16_t* Qb = (bf16_t*)d_ws;
  bf16_t* Kb = Qb + ACT;
  bf16_t* Vb = Kb + ACT;
  bf16_t* Vt = Vb + ACT;
  bf16_t* Ab = Vt + ACT;
  bf16_t* G = Ab + ACT;
  bf16_t* Xq = G + (size_t)BS * SEQ * SEQ;
  bf16_t* Xk = Xq + ACT;
  bf16_t* Xv = Xk + ACT;
  bf16_t* Wqb = Xv + ACT;
  bf16_t* Wkb = Wqb + WSZ;
  bf16_t* Wvb = Wkb + WSZ;
  bf16_t* Wob = Wvb + WSZ;

  prep_kernel<<<1664 + BS * SEQ, 256, 0, stream>>>(
      query, key, value, Wq, Wk, Wv, Wo,
      Xq, Xk, Xv, Wqb, Wkb, Wvb, Wob, wc, G);

  gemm_qkv_kernel<<<dim3(ROWS / 128, DM / 128, 3), 256, 0, stream>>>(
      Xq, Xk, Xv, Wqb, Wkb, Wvb, bq, bk, bv, Qb, Kb, Vb);

  vtrans_kernel<<<dim3(16, 64), 256, 0, stream>>>(Vb, Vt);

  flash_mfma_kernel<<<dim3(SEQ / 128, NH, BS), 256, 0, stream>>>(Qb, Kb, Vt, G, Ab);

  gemm_wo_kernel<<<dim3(ROWS / 64, DM / 128), 256, 0, stream>>>(Ab, Wob, bo, out);
}

// Round 5
// 218.444 us; speedup vs baseline: 1.2074x; 1.2074x over previous
//
#include <hip/hip_runtime.h>
#include <math.h>

// Round 12: pipeline restructure.
//   - flash restored to R9 geometry (best measured: 48.9us) with corrected
//     sync: compute -> s_waitcnt vmcnt(4) (own KV(t+1) DMA done, G prefetch
//     in flight) -> s_barrier at iter BOTTOM.  Race-free (R9 waited after
//     the barrier, relying on prefetch distance).
//   - vtrans kernel ELIMINATED: V-GEMM epilogue writes Vt[(b,h,d)][m]
//     directly -- acc's 4 consecutive rows = 4 consecutive m = contiguous
//     bf16x4 in the transposed layout.  Saves 16MB r/w + one launch.
//   - R11's lesson: LDS staging in flash is for intra-CU fan-out (4 waves
//     share one DMA copy), not HBM.  Keep it.
//   prep / gemm structure otherwise unchanged.

#define BS 8
#define SEQ 1024
#define DM 512
#define NH 8
#define DK 64
#define ROWS (BS * SEQ)

typedef __bf16 bf16_t;
typedef bf16_t bf16x8 __attribute__((ext_vector_type(8)));
typedef bf16_t bf16x4 __attribute__((ext_vector_type(4)));
typedef float f32x4 __attribute__((ext_vector_type(4)));

__device__ inline f32x4 mfma32(bf16x8 a, bf16x8 b, f32x4 c) {
  return __builtin_amdgcn_mfma_f32_16x16x32_bf16(a, b, c, 0, 0, 0);
}

// async global->LDS, 16 bytes/lane.  LDS dest = wave-uniform base + lane*16.
__device__ inline void gload_lds16(const bf16_t* g, bf16_t* l) {
  __builtin_amdgcn_global_load_lds(
      (const __attribute__((address_space(1))) void*)g,
      (__attribute__((address_space(3))) void*)l, 16, 0, 0);
}

// ---------------------------------------------------------------------------
// prep: fused {fp32->bf16 conversion} + {G2 = (1+softmax(wc))*0.125*log2e}.
// blocks [0,1664): cvt (3 act x 512 + 4 wt x 32); [1664, 1664+8192): wc rows.
// ---------------------------------------------------------------------------
__global__ __launch_bounds__(256) void prep_kernel(
    const float* q, const float* k, const float* v,
    const float* wq, const float* wk, const float* wv, const float* wo,
    bf16_t* xq, bf16_t* xk, bf16_t* xv,
    bf16_t* wqb, bf16_t* wkb, bf16_t* wvb, bf16_t* wob,
    const float* __restrict__ wc, bf16_t* __restrict__ G) {
  int bx = blockIdx.x;
  int t = threadIdx.x;
  if (bx < 1664) {
    const float* srcs[7] = {q, k, v, wq, wk, wv, wo};
    bf16_t* dsts[7] = {xq, xk, xv, wqb, wkb, wvb, wob};
    int seg, boff;
    if (bx < 1536) { seg = bx >> 9; boff = bx & 511; }
    else { seg = 3 + ((bx - 1536) >> 5); boff = (bx - 1536) & 31; }
    const float* src = srcs[seg] + (size_t)boff * 8192;
    bf16_t* dst = dsts[seg] + (size_t)boff * 8192;
#pragma unroll
    for (int f = 0; f < 8; ++f) {
      int idx = (f * 256 + t) * 4;
      float4 x = *(const float4*)(src + idx);
      bf16x4 o;
      o[0] = (bf16_t)x.x; o[1] = (bf16_t)x.y; o[2] = (bf16_t)x.z; o[3] = (bf16_t)x.w;
      *(bf16x4*)(dst + idx) = o;
    }
  } else {
    int row = bx - 1664;
    const float* x = wc + (size_t)row * SEQ;
    bf16_t* y = G + (size_t)row * SEQ;
    float4 vv = *(const float4*)(x + t * 4);
    float m = fmaxf(fmaxf(vv.x, vv.y), fmaxf(vv.z, vv.w));
#pragma unroll
    for (int off = 32; off > 0; off >>= 1) m = fmaxf(m, __shfl_xor(m, off, 64));
    __shared__ float sm[4], ss[4];
    int w = t >> 6;
    if ((t & 63) == 0) sm[w] = m;
    __syncthreads();
    m = fmaxf(fmaxf(sm[0], sm[1]), fmaxf(sm[2], sm[3]));
    float4 e;
    e.x = __expf(vv.x - m); e.y = __expf(vv.y - m);
    e.z = __expf(vv.z - m); e.w = __expf(vv.w - m);
    float s = e.x + e.y + e.z + e.w;
#pragma unroll
    for (int off = 32; off > 0; off >>= 1) s += __shfl_xor(s, off, 64);
    if ((t & 63) == 0) ss[w] = s;
    __syncthreads();
    s = ss[0] + ss[1] + ss[2] + ss[3];
    float inv = 1.0f / s;
    const float SC = 0.18033688011112042f;  // 0.125 * log2(e)
    bf16x4 g;
    g[0] = (bf16_t)((1.0f + e.x * inv) * SC);
    g[1] = (bf16_t)((1.0f + e.y * inv) * SC);
    g[2] = (bf16_t)((1.0f + e.z * inv) * SC);
    g[3] = (bf16_t)((1.0f + e.w * inv) * SC);
    *(bf16x4*)(y + t * 4) = g;
  }
}

// ---------------------------------------------------------------------------
// Core bf16 GEMM: C[M,512] = X @ W^T + bias.  BN=128, BK=32, BM in {64,128}.
// VTRANS: write output transposed per-head into Vt[(b*8+h)*64+d][m]
// (acc's 4 consecutive rows = 4 consecutive m = one bf16x4 store).
// ---------------------------------------------------------------------------
template <int BM, bool OUTF32, bool VTRANS>
__device__ inline void gemm_core(const bf16_t* X, const bf16_t* W,
                                 const float* bias, void* Cv,
                                 int mblk, int nblk) {
  __shared__ bf16_t As[2][BM * 32];
  __shared__ bf16_t Bs[2][128 * 32];
  int t = threadIdx.x, lane = t & 63, w = t >> 6;
  int quad = lane >> 4, l15 = lane & 15;
  constexpr int MT = BM / 32;
  int m0w = (w & 1) * (BM / 2), n0w = (w >> 1) * 64;
  int mbase = mblk * BM, nbase = nblk * 128;
  int lr = lane >> 2, l4 = lane & 3;
  f32x4 acc[MT][4] = {};

#pragma unroll
  for (int f = 0; f < BM / 64; ++f) {
    int i = f * 4 + w;
    gload_lds16(X + (size_t)(mbase + i * 16 + lr) * DM + l4 * 8, &As[0][i * 512]);
  }
#pragma unroll
  for (int f = 0; f < 2; ++f) {
    int i = f * 4 + w;
    gload_lds16(W + (size_t)(nbase + i * 16 + lr) * DM + l4 * 8, &Bs[0][i * 512]);
  }

  for (int it = 0; it < 16; ++it) {
    __syncthreads();
    int cb = it & 1;
    if (it + 1 < 16) {
      int kb = (it + 1) * 32, nb = (it + 1) & 1;
#pragma unroll
      for (int f = 0; f < BM / 64; ++f) {
        int i = f * 4 + w;
        gload_lds16(X + (size_t)(mbase + i * 16 + lr) * DM + kb + l4 * 8, &As[nb][i * 512]);
      }
#pragma unroll
      for (int f = 0; f < 2; ++f) {
        int i = f * 4 + w;
        gload_lds16(W + (size_t)(nbase + i * 16 + lr) * DM + kb + l4 * 8, &Bs[nb][i * 512]);
      }
    }
    bf16x8 af[MT], bfr[4];
#pragma unroll
    for (int mt = 0; mt < MT; ++mt)
      af[mt] = *(const bf16x8*)&As[cb][(m0w + mt * 16 + l15) * 32 + quad * 8];
#pragma unroll
    for (int nt = 0; nt < 4; ++nt)
      bfr[nt] = *(const bf16x8*)&Bs[cb][(n0w + nt * 16 + l15) * 32 + quad * 8];
#pragma unroll
    for (int mt = 0; mt < MT; ++mt)
#pragma unroll
      for (int nt = 0; nt < 4; ++nt)
        acc[mt][nt] = mfma32(af[mt], bfr[nt], acc[mt][nt]);
  }

#pragma unroll
  for (int nt = 0; nt < 4; ++nt) {
    int col = nbase + n0w + nt * 16 + l15;
    float bc = bias[col];
#pragma unroll
    for (int mt = 0; mt < MT; ++mt) {
      if (VTRANS) {
        int row0 = mbase + m0w + mt * 16 + quad * 4;
        int b = row0 >> 10, m = row0 & 1023;
        int h = col >> 6, d = col & 63;
        bf16x4 ov;
#pragma unroll
        for (int r = 0; r < 4; ++r) ov[r] = (bf16_t)(acc[mt][nt][r] + bc);
        *(bf16x4*)&((bf16_t*)Cv)[((size_t)((b * NH + h) * DK + d)) * SEQ + m] = ov;
      } else {
#pragma unroll
        for (int r = 0; r < 4; ++r) {
          int row = mbase + m0w + mt * 16 + quad * 4 + r;
          float vv = acc[mt][nt][r] + bc;
          if (OUTF32)
            ((float*)Cv)[(size_t)row * DM + col] = vv;
          else
            ((bf16_t*)Cv)[(size_t)row * DM + col] = (bf16_t)vv;
        }
      }
    }
  }
}

__global__ __launch_bounds__(256) void gemm_qkv_kernel(
    const bf16_t* xq, const bf16_t* xk, const bf16_t* xv,
    const bf16_t* wq, const bf16_t* wk, const bf16_t* wv,
    const float* bq, const float* bk, const float* bv,
    bf16_t* cq, bf16_t* ck, bf16_t* vt) {
  int z = blockIdx.z;
  if (z == 0)
    gemm_core<128, false, false>(xq, wq, bq, cq, blockIdx.x, blockIdx.y);
  else if (z == 1)
    gemm_core<128, false, false>(xk, wk, bk, ck, blockIdx.x, blockIdx.y);
  else
    gemm_core<128, false, true>(xv, wv, bv, vt, blockIdx.x, blockIdx.y);
}

__global__ __launch_bounds__(256) void gemm_wo_kernel(const bf16_t* X, const bf16_t* W,
                                                      const float* bias, float* C) {
  gemm_core<64, true, false>(X, W, bias, C, blockIdx.x, blockIdx.y);
}

// ---------------------------------------------------------------------------
// Flash attention, R12 (= R9 geometry, corrected sync).  Block: 64 q x (h,b),
// 4 waves, 16 q/wave, 16x16x32 MFMA.
//   S^T = mfma(K,Q); p = exp2(s * G2) (no max subtraction, bounded scores);
//   wave-private swizzled LDS P; PV from swizzled Vs.
//   Sync per iter: issue KV(t+1) -> compute -> vmcnt(4) (own DMA done,
//   G(t+1) in flight) -> s_barrier.  One barrier/iter, race-free.
//   XCD swizzle: XCD x owns batch b=x -> K/V/G panels single-L2.
// LDS: Ks 16K + Vs 16K + Ps 8K = 40KB -> 4 blocks/CU.
// ---------------------------------------------------------------------------
__global__ __launch_bounds__(256, 4) void flash_mfma_kernel(
    const bf16_t* __restrict__ Qb, const bf16_t* __restrict__ Kb,
    const bf16_t* __restrict__ Vt, const bf16_t* __restrict__ G,
    bf16_t* __restrict__ Ab) {
  int flat = blockIdx.x + 16 * (blockIdx.y + 8 * blockIdx.z);
  int l = (flat & 7) * 128 + (flat >> 3);
  int qt = l & 15, h = (l >> 4) & 7, b = l >> 7;

  __shared__ bf16_t Ks[2][64 * 64];  // [kv][d], 16B-chunk col ^ (row&7)
  __shared__ bf16_t Vs[2][64 * 64];  // [d][kv], 16B-chunk col ^ (row&7)
  __shared__ bf16_t Ps[4][16 * 64];  // per-wave [q][kv], swizzled
  int t = threadIdx.x, lane = t & 63, w = t >> 6;
  int quad = lane >> 4, l15 = lane & 15;
  int k7 = l15 & 7;

  int srow[2], scol[2];
#pragma unroll
  for (int f = 0; f < 2; ++f) {
    int idx = f * 256 + t;
    int r = idx >> 3, p = idx & 7;
    srow[f] = r;
    scol[f] = ((p ^ (r & 7)) * 8);
  }
  const bf16_t* Kbase = Kb + (size_t)(b * SEQ) * DM + h * DK;
  const bf16_t* Vbase = Vt + (size_t)((b * NH + h) * DK) * SEQ;

  // Q fragments straight from global (once).
  size_t qrow_g = (size_t)(b * SEQ + qt * 64 + w * 16 + l15) * DM + h * DK;
  bf16x8 aq0 = *(const bf16x8*)&Qb[qrow_g + quad * 8];
  bf16x8 aq1 = *(const bf16x8*)&Qb[qrow_g + 32 + quad * 8];

  const size_t grow = (size_t)(b * SEQ + qt * 64 + w * 16 + l15) * SEQ;
  bf16x4 greg[4];
#pragma unroll
  for (int ct = 0; ct < 4; ++ct)
    greg[ct] = *(const bf16x4*)&G[grow + ct * 16 + quad * 4];

  // prologue: stage tile 0 into buffer 0; drain; publish.
#pragma unroll
  for (int f = 0; f < 2; ++f) {
    int cbase = (f * 256 + w * 64) * 8;
    gload_lds16(Kbase + (size_t)srow[f] * DM + scol[f], &Ks[0][cbase]);
    gload_lds16(Vbase + (size_t)srow[f] * SEQ + scol[f], &Vs[0][cbase]);
  }
  asm volatile("s_waitcnt vmcnt(0)" ::: "memory");
  asm volatile("s_barrier" ::: "memory");

  float l_st = 0.f;
  f32x4 o[4] = {};

  for (int mt = 0; mt < 16; ++mt) {
    int cb = mt & 1;
    if (mt < 15) {  // WAR-safe: barrier at bottom of iter mt-1 passed
      int nb = cb ^ 1;
      const bf16_t* Kn = Kbase + (size_t)(mt + 1) * 64 * DM;
      const bf16_t* Vn = Vbase + (mt + 1) * 64;
#pragma unroll
      for (int f = 0; f < 2; ++f) {
        int cbase = (f * 256 + w * 64) * 8;
        gload_lds16(Kn + (size_t)srow[f] * DM + scol[f], &Ks[nb][cbase]);
        gload_lds16(Vn + (size_t)srow[f] * SEQ + scol[f], &Vs[nb][cbase]);
      }
      asm volatile("" ::: "memory");  // keep gloads oldest in vmcnt queue
    }

    // QK^T: S^T rows = kv (ct*16 + quad*4 + r), cols = q (l15)
    f32x4 s[4];
    __builtin_amdgcn_s_setprio(1);
#pragma unroll
    for (int ct = 0; ct < 4; ++ct) {
      int r = ct * 16 + l15;
      int sw = r & 7;  // == k7
      bf16x8 ak0 = *(const bf16x8*)&Ks[cb][r * 64 + ((quad ^ sw) * 8)];
      bf16x8 ak1 = *(const bf16x8*)&Ks[cb][r * 64 + (((4 + quad) ^ sw) * 8)];
      f32x4 z = {};
      s[ct] = mfma32(ak1, aq1, mfma32(ak0, aq0, z));
    }
    __builtin_amdgcn_s_setprio(0);

    // p = exp2(s * g2); no max subtraction (bounded scores), no rescale.
    float rs = 0.f;
#pragma unroll
    for (int ct = 0; ct < 4; ++ct) {
      bf16x4 pb;
#pragma unroll
      for (int r = 0; r < 4; ++r) {
        float p = __builtin_amdgcn_exp2f(s[ct][r] * (float)greg[ct][r]);
        pb[r] = (bf16_t)p;
        rs += p;
      }
      int chunk = (2 * ct + (quad >> 1)) ^ k7;
      *(bf16x4*)&Ps[w][l15 * 64 + chunk * 8 + (quad & 1) * 4] = pb;
    }
    // greg dead -> prefetch G(mt+1); stays in flight across the barrier.
    if (mt < 15) {
#pragma unroll
      for (int ct = 0; ct < 4; ++ct)
        greg[ct] = *(const bf16x4*)&G[grow + (mt + 1) * 64 + ct * 16 + quad * 4];
    }
    rs += __shfl_xor(rs, 16, 64);
    rs += __shfl_xor(rs, 32, 64);
    l_st += rs;

    // PV: o[dt] += V^T[d][kv] . P[q][kv]
    __builtin_amdgcn_s_setprio(1);
#pragma unroll
    for (int c = 0; c < 2; ++c) {
      int pchunk = (4 * c + quad) ^ k7;
      bf16x8 bp = *(const bf16x8*)&Ps[w][l15 * 64 + pchunk * 8];
#pragma unroll
      for (int dt = 0; dt < 4; ++dt) {
        int d = dt * 16 + l15;
        int vchunk = (4 * c + quad) ^ (d & 7);
        bf16x8 av = *(const bf16x8*)&Vs[cb][d * 64 + vchunk * 8];
        o[dt] = mfma32(av, bp, o[dt]);
      }
    }
    __builtin_amdgcn_s_setprio(0);

    if (mt < 15) {
      // own KV(t+1) DMA complete (oldest 4; G prefetch stays in flight),
      // THEN barrier: after it, every wave's staging for t+1 is visible.
      asm volatile("s_waitcnt vmcnt(4)" ::: "memory");
      asm volatile("s_barrier" ::: "memory");
    }
  }

  float linv = 1.0f / l_st;
#pragma unroll
  for (int dt = 0; dt < 4; ++dt) {
    bf16x4 ov;
#pragma unroll
    for (int r = 0; r < 4; ++r) ov[r] = (bf16_t)(o[dt][r] * linv);
    *(bf16x4*)&Ab[qrow_g + dt * 16 + quad * 4] = ov;
  }
}

// ---------------------------------------------------------------------------
extern "C" void kernel_launch(void* const* d_in, const int* in_sizes, int n_in,
                              void* d_out, int out_size, void* d_ws, size_t ws_size,
                              hipStream_t stream) {
  const float* query = (const float*)d_in[0];
  const float* key = (const float*)d_in[1];
  const float* value = (const float*)d_in[2];
  const float* wc = (const float*)d_in[3];
  const float* Wq = (const float*)d_in[4];
  const float* bq = (const float*)d_in[5];
  const float* Wk = (const float*)d_in[6];
  const float* bk = (const float*)d_in[7];
  const float* Wv = (const float*)d_in[8];
  const float* bv = (const float*)d_in[9];
  const float* Wo = (const float*)d_in[10];
  const float* bo = (const float*)d_in[11];
  float* out = (float*)d_out;

  const size_t ACT = (size_t)ROWS * DM;
  const size_t WSZ = (size_t)DM * DM;
  bf16_t* Qb = (bf16_t*)d_ws;
  bf16_t* Kb = Qb + ACT;
  bf16_t* Vb = Kb + ACT;  // unused (kept for layout stability)
  bf16_t* Vt = Vb + ACT;
  bf16_t* Ab = Vt + ACT;
  bf16_t* G = Ab + ACT;
  bf16_t* Xq = G + (size_t)BS * SEQ * SEQ;
  bf16_t* Xk = Xq + ACT;
  bf16_t* Xv = Xk + ACT;
  bf16_t* Wqb = Xv + ACT;
  bf16_t* Wkb = Wqb + WSZ;
  bf16_t* Wvb = Wkb + WSZ;
  bf16_t* Wob = Wvb + WSZ;

  prep_kernel<<<1664 + BS * SEQ, 256, 0, stream>>>(
      query, key, value, Wq, Wk, Wv, Wo,
      Xq, Xk, Xv, Wqb, Wkb, Wvb, Wob, wc, G);

  gemm_qkv_kernel<<<dim3(ROWS / 128, DM / 128, 3), 256, 0, stream>>>(
      Xq, Xk, Xv, Wqb, Wkb, Wvb, bq, bk, bv, Qb, Kb, Vt);

  flash_mfma_kernel<<<dim3(SEQ / 64, NH, BS), 256, 0, stream>>>(Qb, Kb, Vt, G, Ab);

  gemm_wo_kernel<<<dim3(ROWS / 64, DM / 128), 256, 0, stream>>>(Ab, Wob, bo, out);
}

// Round 6
// 210.919 us; speedup vs baseline: 1.2505x; 1.0357x over previous
//
#include <hip/hip_runtime.h>
#include <math.h>

// Round 13: store-path round.
//   - gemm_core: single smem union (staging || epilogue bounce buffer).
//     wo: f32 tile staged to LDS -> float4 coalesced stores (was 4x64B
//     segments/instr).  qkv z=2: transposed tile staged to LDS -> bf16x8
//     row stores (was 16x8B segments/instr, ~4x write amplification).
//   - qkv: ONE gemm_core instantiation, vtrans is a runtime flag.
//   - flash / prep unchanged from R12 (flash proven 49.0us).

#define BS 8
#define SEQ 1024
#define DM 512
#define NH 8
#define DK 64
#define ROWS (BS * SEQ)

typedef __bf16 bf16_t;
typedef bf16_t bf16x8 __attribute__((ext_vector_type(8)));
typedef bf16_t bf16x4 __attribute__((ext_vector_type(4)));
typedef float f32x4 __attribute__((ext_vector_type(4)));

__device__ inline f32x4 mfma32(bf16x8 a, bf16x8 b, f32x4 c) {
  return __builtin_amdgcn_mfma_f32_16x16x32_bf16(a, b, c, 0, 0, 0);
}

// async global->LDS, 16 bytes/lane.  LDS dest = wave-uniform base + lane*16.
__device__ inline void gload_lds16(const bf16_t* g, bf16_t* l) {
  __builtin_amdgcn_global_load_lds(
      (const __attribute__((address_space(1))) void*)g,
      (__attribute__((address_space(3))) void*)l, 16, 0, 0);
}

// ---------------------------------------------------------------------------
// prep: fused {fp32->bf16 conversion} + {G2 = (1+softmax(wc))*0.125*log2e}.
// ---------------------------------------------------------------------------
__global__ __launch_bounds__(256) void prep_kernel(
    const float* q, const float* k, const float* v,
    const float* wq, const float* wk, const float* wv, const float* wo,
    bf16_t* xq, bf16_t* xk, bf16_t* xv,
    bf16_t* wqb, bf16_t* wkb, bf16_t* wvb, bf16_t* wob,
    const float* __restrict__ wc, bf16_t* __restrict__ G) {
  int bx = blockIdx.x;
  int t = threadIdx.x;
  if (bx < 1664) {
    const float* srcs[7] = {q, k, v, wq, wk, wv, wo};
    bf16_t* dsts[7] = {xq, xk, xv, wqb, wkb, wvb, wob};
    int seg, boff;
    if (bx < 1536) { seg = bx >> 9; boff = bx & 511; }
    else { seg = 3 + ((bx - 1536) >> 5); boff = (bx - 1536) & 31; }
    const float* src = srcs[seg] + (size_t)boff * 8192;
    bf16_t* dst = dsts[seg] + (size_t)boff * 8192;
#pragma unroll
    for (int f = 0; f < 8; ++f) {
      int idx = (f * 256 + t) * 4;
      float4 x = *(const float4*)(src + idx);
      bf16x4 o;
      o[0] = (bf16_t)x.x; o[1] = (bf16_t)x.y; o[2] = (bf16_t)x.z; o[3] = (bf16_t)x.w;
      *(bf16x4*)(dst + idx) = o;
    }
  } else {
    int row = bx - 1664;
    const float* x = wc + (size_t)row * SEQ;
    bf16_t* y = G + (size_t)row * SEQ;
    float4 vv = *(const float4*)(x + t * 4);
    float m = fmaxf(fmaxf(vv.x, vv.y), fmaxf(vv.z, vv.w));
#pragma unroll
    for (int off = 32; off > 0; off >>= 1) m = fmaxf(m, __shfl_xor(m, off, 64));
    __shared__ float sm[4], ss[4];
    int w = t >> 6;
    if ((t & 63) == 0) sm[w] = m;
    __syncthreads();
    m = fmaxf(fmaxf(sm[0], sm[1]), fmaxf(sm[2], sm[3]));
    float4 e;
    e.x = __expf(vv.x - m); e.y = __expf(vv.y - m);
    e.z = __expf(vv.z - m); e.w = __expf(vv.w - m);
    float s = e.x + e.y + e.z + e.w;
#pragma unroll
    for (int off = 32; off > 0; off >>= 1) s += __shfl_xor(s, off, 64);
    if ((t & 63) == 0) ss[w] = s;
    __syncthreads();
    s = ss[0] + ss[1] + ss[2] + ss[3];
    float inv = 1.0f / s;
    const float SC = 0.18033688011112042f;  // 0.125 * log2(e)
    bf16x4 g;
    g[0] = (bf16_t)((1.0f + e.x * inv) * SC);
    g[1] = (bf16_t)((1.0f + e.y * inv) * SC);
    g[2] = (bf16_t)((1.0f + e.z * inv) * SC);
    g[3] = (bf16_t)((1.0f + e.w * inv) * SC);
    *(bf16x4*)(y + t * 4) = g;
  }
}

// ---------------------------------------------------------------------------
// Core bf16 GEMM: C[M,512] = X @ W^T + bias.  BN=128, BK=32, BM in {64,128}.
// WO (compile-time): f32 output through LDS -> coalesced float4 stores.
// vtrans (runtime): bf16 output transposed per-head into Vt[(b,h,d)][m],
//   staged through LDS -> coalesced bf16x8 row stores.
// smem is a union: staging (As|Bs) during K-loop, bounce buffer in epilogue.
// ---------------------------------------------------------------------------
template <int BM, bool WO>
__device__ inline void gemm_core(const bf16_t* X, const bf16_t* W,
                                 const float* bias, void* Cv,
                                 int mblk, int nblk, bool vtrans) {
  constexpr int STAGE_B = (2 * BM * 32 + 2 * 128 * 32) * 2;
  constexpr int EPI_B = WO ? BM * 132 * 4 : 128 * 136 * 2;
  constexpr int SMEM_B = STAGE_B > EPI_B ? STAGE_B : EPI_B;
  __shared__ __align__(16) char smem[SMEM_B];
  bf16_t* As = (bf16_t*)smem;                 // [2][BM*32]
  bf16_t* Bs = (bf16_t*)smem + 2 * BM * 32;   // [2][128*32]

  int t = threadIdx.x, lane = t & 63, w = t >> 6;
  int quad = lane >> 4, l15 = lane & 15;
  constexpr int MT = BM / 32;
  int m0w = (w & 1) * (BM / 2), n0w = (w >> 1) * 64;
  int mbase = mblk * BM, nbase = nblk * 128;
  int lr = lane >> 2, l4 = lane & 3;
  f32x4 acc[MT][4] = {};

#pragma unroll
  for (int f = 0; f < BM / 64; ++f) {
    int i = f * 4 + w;
    gload_lds16(X + (size_t)(mbase + i * 16 + lr) * DM + l4 * 8, &As[i * 512]);
  }
#pragma unroll
  for (int f = 0; f < 2; ++f) {
    int i = f * 4 + w;
    gload_lds16(W + (size_t)(nbase + i * 16 + lr) * DM + l4 * 8, &Bs[i * 512]);
  }

  for (int it = 0; it < 16; ++it) {
    __syncthreads();
    int cb = it & 1;
    if (it + 1 < 16) {
      int kb = (it + 1) * 32, nb = (it + 1) & 1;
#pragma unroll
      for (int f = 0; f < BM / 64; ++f) {
        int i = f * 4 + w;
        gload_lds16(X + (size_t)(mbase + i * 16 + lr) * DM + kb + l4 * 8,
                    &As[nb * BM * 32 + i * 512]);
      }
#pragma unroll
      for (int f = 0; f < 2; ++f) {
        int i = f * 4 + w;
        gload_lds16(W + (size_t)(nbase + i * 16 + lr) * DM + kb + l4 * 8,
                    &Bs[nb * 128 * 32 + i * 512]);
      }
    }
    bf16x8 af[MT], bfr[4];
#pragma unroll
    for (int mt = 0; mt < MT; ++mt)
      af[mt] = *(const bf16x8*)&As[cb * BM * 32 + (m0w + mt * 16 + l15) * 32 + quad * 8];
#pragma unroll
    for (int nt = 0; nt < 4; ++nt)
      bfr[nt] = *(const bf16x8*)&Bs[cb * 128 * 32 + (n0w + nt * 16 + l15) * 32 + quad * 8];
#pragma unroll
    for (int mt = 0; mt < MT; ++mt)
#pragma unroll
      for (int nt = 0; nt < 4; ++nt)
        acc[mt][nt] = mfma32(af[mt], bfr[nt], acc[mt][nt]);
  }

  if (WO) {
    // f32 tile -> LDS -> coalesced float4 stores.
    __syncthreads();  // staging reads done in all waves
    float* Cs = (float*)smem;  // [BM][132]
#pragma unroll
    for (int nt = 0; nt < 4; ++nt) {
      int colL = n0w + nt * 16 + l15;
      float bc = bias[nbase + colL];
#pragma unroll
      for (int mt = 0; mt < MT; ++mt)
#pragma unroll
        for (int r = 0; r < 4; ++r)
          Cs[(m0w + mt * 16 + quad * 4 + r) * 132 + colL] = acc[mt][nt][r] + bc;
    }
    __syncthreads();
    constexpr int NP = BM * 128 / 4 / 256;  // float4s per thread
#pragma unroll
    for (int p = 0; p < NP; ++p) {
      int flat = p * 256 + t;
      int row = flat >> 5, c4 = (flat & 31) * 4;
      float4 vv = *(const float4*)&Cs[row * 132 + c4];
      *(float4*)&((float*)Cv)[(size_t)(mbase + row) * DM + nbase + c4] = vv;
    }
  } else if (vtrans) {
    // transposed bf16 tile -> LDS -> coalesced bf16x8 row stores into Vt.
    __syncthreads();
    bf16_t* Ts = (bf16_t*)smem;  // [128 col][136 m]
#pragma unroll
    for (int nt = 0; nt < 4; ++nt) {
      int colL = n0w + nt * 16 + l15;
      float bc = bias[nbase + colL];
#pragma unroll
      for (int mt = 0; mt < MT; ++mt) {
        bf16x4 ov;
#pragma unroll
        for (int r = 0; r < 4; ++r) ov[r] = (bf16_t)(acc[mt][nt][r] + bc);
        *(bf16x4*)&Ts[colL * 136 + m0w + mt * 16 + quad * 4] = ov;
      }
    }
    __syncthreads();
    int b = mbase >> 10;       // BM=128 divides SEQ -> block within one batch
    int m0 = mbase & 1023;
#pragma unroll
    for (int p = 0; p < 8; ++p) {
      int flat = p * 256 + t;
      int colL = flat >> 4, m8 = (flat & 15) * 8;
      bf16x8 vv = *(const bf16x8*)&Ts[colL * 136 + m8];
      int colG = nbase + colL;
      int hh = colG >> 6, dd = colG & 63;
      *(bf16x8*)&((bf16_t*)Cv)[((size_t)(b * NH + hh) * DK + dd) * SEQ + m0 + m8] = vv;
    }
  } else {
#pragma unroll
    for (int nt = 0; nt < 4; ++nt) {
      int col = nbase + n0w + nt * 16 + l15;
      float bc = bias[col];
#pragma unroll
      for (int mt = 0; mt < MT; ++mt)
#pragma unroll
        for (int r = 0; r < 4; ++r) {
          int row = mbase + m0w + mt * 16 + quad * 4 + r;
          ((bf16_t*)Cv)[(size_t)row * DM + col] = (bf16_t)(acc[mt][nt][r] + bc);
        }
    }
  }
}

__global__ __launch_bounds__(256) void gemm_qkv_kernel(
    const bf16_t* xq, const bf16_t* xk, const bf16_t* xv,
    const bf16_t* wq, const bf16_t* wk, const bf16_t* wv,
    const float* bq, const float* bk, const float* bv,
    bf16_t* cq, bf16_t* ck, bf16_t* vt) {
  const bf16_t* Xarr[3] = {xq, xk, xv};
  const bf16_t* Warr[3] = {wq, wk, wv};
  const float* barr[3] = {bq, bk, bv};
  bf16_t* Carr[3] = {cq, ck, vt};
  int z = blockIdx.z;
  gemm_core<128, false>(Xarr[z], Warr[z], barr[z], Carr[z],
                        blockIdx.x, blockIdx.y, z == 2);
}

__global__ __launch_bounds__(256) void gemm_wo_kernel(const bf16_t* X, const bf16_t* W,
                                                      const float* bias, float* C) {
  gemm_core<64, true>(X, W, bias, C, blockIdx.x, blockIdx.y, false);
}

// ---------------------------------------------------------------------------
// Flash attention (R12, unchanged -- proven 49.0us).  Block: 64 q x (h,b),
// 4 waves, 16 q/wave, 16x16x32 MFMA, one barrier/iter, race-free sync.
// ---------------------------------------------------------------------------
__global__ __launch_bounds__(256, 4) void flash_mfma_kernel(
    const bf16_t* __restrict__ Qb, const bf16_t* __restrict__ Kb,
    const bf16_t* __restrict__ Vt, const bf16_t* __restrict__ G,
    bf16_t* __restrict__ Ab) {
  int flat = blockIdx.x + 16 * (blockIdx.y + 8 * blockIdx.z);
  int l = (flat & 7) * 128 + (flat >> 3);
  int qt = l & 15, h = (l >> 4) & 7, b = l >> 7;

  __shared__ bf16_t Ks[2][64 * 64];  // [kv][d], 16B-chunk col ^ (row&7)
  __shared__ bf16_t Vs[2][64 * 64];  // [d][kv], 16B-chunk col ^ (row&7)
  __shared__ bf16_t Ps[4][16 * 64];  // per-wave [q][kv], swizzled
  int t = threadIdx.x, lane = t & 63, w = t >> 6;
  int quad = lane >> 4, l15 = lane & 15;
  int k7 = l15 & 7;

  int srow[2], scol[2];
#pragma unroll
  for (int f = 0; f < 2; ++f) {
    int idx = f * 256 + t;
    int r = idx >> 3, p = idx & 7;
    srow[f] = r;
    scol[f] = ((p ^ (r & 7)) * 8);
  }
  const bf16_t* Kbase = Kb + (size_t)(b * SEQ) * DM + h * DK;
  const bf16_t* Vbase = Vt + (size_t)((b * NH + h) * DK) * SEQ;

  size_t qrow_g = (size_t)(b * SEQ + qt * 64 + w * 16 + l15) * DM + h * DK;
  bf16x8 aq0 = *(const bf16x8*)&Qb[qrow_g + quad * 8];
  bf16x8 aq1 = *(const bf16x8*)&Qb[qrow_g + 32 + quad * 8];

  const size_t grow = (size_t)(b * SEQ + qt * 64 + w * 16 + l15) * SEQ;
  bf16x4 greg[4];
#pragma unroll
  for (int ct = 0; ct < 4; ++ct)
    greg[ct] = *(const bf16x4*)&G[grow + ct * 16 + quad * 4];

#pragma unroll
  for (int f = 0; f < 2; ++f) {
    int cbase = (f * 256 + w * 64) * 8;
    gload_lds16(Kbase + (size_t)srow[f] * DM + scol[f], &Ks[0][cbase]);
    gload_lds16(Vbase + (size_t)srow[f] * SEQ + scol[f], &Vs[0][cbase]);
  }
  asm volatile("s_waitcnt vmcnt(0)" ::: "memory");
  asm volatile("s_barrier" ::: "memory");

  float l_st = 0.f;
  f32x4 o[4] = {};

  for (int mt = 0; mt < 16; ++mt) {
    int cb = mt & 1;
    if (mt < 15) {
      int nb = cb ^ 1;
      const bf16_t* Kn = Kbase + (size_t)(mt + 1) * 64 * DM;
      const bf16_t* Vn = Vbase + (mt + 1) * 64;
#pragma unroll
      for (int f = 0; f < 2; ++f) {
        int cbase = (f * 256 + w * 64) * 8;
        gload_lds16(Kn + (size_t)srow[f] * DM + scol[f], &Ks[nb][cbase]);
        gload_lds16(Vn + (size_t)srow[f] * SEQ + scol[f], &Vs[nb][cbase]);
      }
      asm volatile("" ::: "memory");
    }

    f32x4 s[4];
    __builtin_amdgcn_s_setprio(1);
#pragma unroll
    for (int ct = 0; ct < 4; ++ct) {
      int r = ct * 16 + l15;
      int sw = r & 7;
      bf16x8 ak0 = *(const bf16x8*)&Ks[cb][r * 64 + ((quad ^ sw) * 8)];
      bf16x8 ak1 = *(const bf16x8*)&Ks[cb][r * 64 + (((4 + quad) ^ sw) * 8)];
      f32x4 z = {};
      s[ct] = mfma32(ak1, aq1, mfma32(ak0, aq0, z));
    }
    __builtin_amdgcn_s_setprio(0);

    float rs = 0.f;
#pragma unroll
    for (int ct = 0; ct < 4; ++ct) {
      bf16x4 pb;
#pragma unroll
      for (int r = 0; r < 4; ++r) {
        float p = __builtin_amdgcn_exp2f(s[ct][r] * (float)greg[ct][r]);
        pb[r] = (bf16_t)p;
        rs += p;
      }
      int chunk = (2 * ct + (quad >> 1)) ^ k7;
      *(bf16x4*)&Ps[w][l15 * 64 + chunk * 8 + (quad & 1) * 4] = pb;
    }
    if (mt < 15) {
#pragma unroll
      for (int ct = 0; ct < 4; ++ct)
        greg[ct] = *(const bf16x4*)&G[grow + (mt + 1) * 64 + ct * 16 + quad * 4];
    }
    rs += __shfl_xor(rs, 16, 64);
    rs += __shfl_xor(rs, 32, 64);
    l_st += rs;

    __builtin_amdgcn_s_setprio(1);
#pragma unroll
    for (int c = 0; c < 2; ++c) {
      int pchunk = (4 * c + quad) ^ k7;
      bf16x8 bp = *(const bf16x8*)&Ps[w][l15 * 64 + pchunk * 8];
#pragma unroll
      for (int dt = 0; dt < 4; ++dt) {
        int d = dt * 16 + l15;
        int vchunk = (4 * c + quad) ^ (d & 7);
        bf16x8 av = *(const bf16x8*)&Vs[cb][d * 64 + vchunk * 8];
        o[dt] = mfma32(av, bp, o[dt]);
      }
    }
    __builtin_amdgcn_s_setprio(0);

    if (mt < 15) {
      asm volatile("s_waitcnt vmcnt(4)" ::: "memory");
      asm volatile("s_barrier" ::: "memory");
    }
  }

  float linv = 1.0f / l_st;
#pragma unroll
  for (int dt = 0; dt < 4; ++dt) {
    bf16x4 ov;
#pragma unroll
    for (int r = 0; r < 4; ++r) ov[r] = (bf16_t)(o[dt][r] * linv);
    *(bf16x4*)&Ab[qrow_g + dt * 16 + quad * 4] = ov;
  }
}

// ---------------------------------------------------------------------------
extern "C" void kernel_launch(void* const* d_in, const int* in_sizes, int n_in,
                              void* d_out, int out_size, void* d_ws, size_t ws_size,
                              hipStream_t stream) {
  const float* query = (const float*)d_in[0];
  const float* key = (const float*)d_in[1];
  const float* value = (const float*)d_in[2];
  const float* wc = (const float*)d_in[3];
  const float* Wq = (const float*)d_in[4];
  const float* bq = (const float*)d_in[5];
  const float* Wk = (const float*)d_in[6];
  const float* bk = (const float*)d_in[7];
  const float* Wv = (const float*)d_in[8];
  const float* bv = (const float*)d_in[9];
  const float* Wo = (const float*)d_in[10];
  const float* bo = (const float*)d_in[11];
  float* out = (float*)d_out;

  const size_t ACT = (size_t)ROWS * DM;
  const size_t WSZ = (size_t)DM * DM;
  bf16_t* Qb = (bf16_t*)d_ws;
  bf16_t* Kb = Qb + ACT;
  bf16_t* Vb = Kb + ACT;  // unused (layout stability)
  bf16_t* Vt = Vb + ACT;
  bf16_t* Ab = Vt + ACT;
  bf16_t* G = Ab + ACT;
  bf16_t* Xq = G + (size_t)BS * SEQ * SEQ;
  bf16_t* Xk = Xq + ACT;
  bf16_t* Xv = Xk + ACT;
  bf16_t* Wqb = Xv + ACT;
  bf16_t* Wkb = Wqb + WSZ;
  bf16_t* Wvb = Wkb + WSZ;
  bf16_t* Wob = Wvb + WSZ;

  prep_kernel<<<1664 + BS * SEQ, 256, 0, stream>>>(
      query, key, value, Wq, Wk, Wv, Wo,
      Xq, Xk, Xv, Wqb, Wkb, Wvb, Wob, wc, G);

  gemm_qkv_kernel<<<dim3(ROWS / 128, DM / 128, 3), 256, 0, stream>>>(
      Xq, Xk, Xv, Wqb, Wkb, Wvb, bq, bk, bv, Qb, Kb, Vt);

  flash_mfma_kernel<<<dim3(SEQ / 64, NH, BS), 256, 0, stream>>>(Qb, Kb, Vt, G, Ab);

  gemm_wo_kernel<<<dim3(ROWS / 64, DM / 128), 256, 0, stream>>>(Ab, Wob, bo, out);
}